// Round 10
// baseline (244.715 us; speedup 1.0000x reference)
//
#include <hip/hip_runtime.h>
#include <hip/hip_fp16.h>
#include <math.h>

#define SS 2048
#define DD 512
#define NH 8
#define HD 64

typedef __attribute__((ext_vector_type(8))) short frag_ab;     // 8 fp16 (x32 A/B)
typedef __attribute__((ext_vector_type(4))) float frag_cd;     // 4 fp32 (C/D)
typedef __attribute__((ext_vector_type(4))) _Float16 frag_b4;  // 4 fp16 (x16 A/B)

static __device__ inline unsigned int pack_h2(float x, float y) {
    __half2 t = __floats2half2_rn(x, y);   // x -> low half
    return *(unsigned int*)&t;
}

// ============================================================================
// R20: FUSED kernel with SLAB-LOCAL sync (fix of R19's barrier pathology).
// R19 post-mortem: global 512-way barrier with s_sleep(2) polling = fabric
// convoy on one cacheline (~100us); numerics passed -> fence pattern correct.
// R20: attn block (qt,h,b) consumes only q_h[b,:,h*64..h*64+64] = 16 gemm
// tiles.  Phase 1 remapped so block bid computes tile (bm=b*16+qt, bn=h):
// its own tile IS its Q rows, and the 16 blocks of slab (b,h) are exactly its
// consumers.  Sync = 32 per-slab counters, 16 arrivers + 16 pollers each,
// s_sleep(32) polls.  Fence usage byte-identical to R19 (proven).  Slabs
// proceed independently -> gemm tail overlaps attn start.
// Measured budget (R19): harness fixed overhead ~43us; gemm+gap ~27us.
// ============================================================================
__global__ __launch_bounds__(512, 4) void fused_kernel(const float* __restrict__ x,
                                                       const float* __restrict__ w,
                                                       unsigned short* __restrict__ qh,
                                                       float* __restrict__ out,
                                                       unsigned int* __restrict__ bar) {
    __shared__ __align__(16) unsigned char LDSB[69632];
    const int tid = threadIdx.x;
    const int lane = tid & 63, wv = tid >> 6;
    const int a = lane & 15, g = lane >> 4;
    const int bid = blockIdx.x;       // 512
    const int qt = bid & 15;
    const int h  = (bid >> 4) & 7;
    const int b  = bid >> 7;
    const int slab = b * 8 + h;       // 32 slabs x 16 blocks

    // ---------------- phase 1: GEMM tile (bm = b*16+qt, bn = h) ----------------
    {
        unsigned short* Ah = (unsigned short*)LDSB;            // [2][128*72] 36864 B
        unsigned short* Bt = (unsigned short*)(LDSB + 36864);  // [2][64*72]  18432 B
        const int bm = b * 16 + qt, bn = h;
        const int wr = wv >> 1, wc = wv & 1;     // wave tile: rows 32*wr.., cols 32*wc..

        frag_cd acc[2][2] = {};                  // [mt][nt]
        const int ar = tid >> 4;                 // A: rows ar+32i, feats (tid&15)*4..+3
        const int ac = (tid & 15) * 4;
        const int bnw = tid & 63;                // B: col n, k-rows 8c..8c+7
        const int bc  = tid >> 6;
        const int bp  = (bc + 2 * (bnw & 7)) & 7;

        float4 av[4];
        float  bw[8];

        auto load_tiles = [&](int k0) {
            #pragma unroll
            for (int i = 0; i < 4; ++i)
                av[i] = *(const float4*)(x + (size_t)(bm * 128 + ar + 32 * i) * 512 + k0 + ac);
            #pragma unroll
            for (int j = 0; j < 8; ++j)
                bw[j] = w[(size_t)(k0 + bc * 8 + j) * 512 + bn * 64 + bnw];
        };
        auto stage_tiles = [&](int buf) {
            #pragma unroll
            for (int i = 0; i < 4; ++i) {
                uint2 hh = { pack_h2(av[i].x, av[i].y), pack_h2(av[i].z, av[i].w) };
                *(uint2*)&Ah[buf * 9216 + (ar + 32 * i) * 72 + ac] = hh;
            }
            unsigned int tb[4];
            #pragma unroll
            for (int j = 0; j < 4; ++j)
                tb[j] = pack_h2(bw[2 * j], bw[2 * j + 1]);
            *(uint4*)&Bt[buf * 4608 + bnw * 72 + bp * 8] = *(uint4*)tb;
        };

        load_tiles(0);
        stage_tiles(0);
        load_tiles(64);
        __syncthreads();

        for (int it = 0; it < 8; ++it) {
            const int cur = it & 1;
            if (it < 7) stage_tiles(cur ^ 1);
            if (it < 6) load_tiles((it + 2) * 64);
            #pragma unroll
            for (int kh = 0; kh < 2; ++kh) {
                frag_ab bf[2], af[2];
                #pragma unroll
                for (int nt = 0; nt < 2; ++nt) {
                    const int nr = wc * 32 + nt * 16 + a;
                    const int pr = ((kh * 4 + g) + 2 * (nr & 7)) & 7;
                    bf[nt] = *(const frag_ab*)&Bt[cur * 4608 + nr * 72 + pr * 8];
                }
                #pragma unroll
                for (int mt = 0; mt < 2; ++mt)
                    af[mt] = *(const frag_ab*)&Ah[cur * 9216 + (wr * 32 + mt * 16 + a) * 72 + kh * 32 + g * 8];
                #pragma unroll
                for (int mt = 0; mt < 2; ++mt)
                    #pragma unroll
                    for (int nt = 0; nt < 2; ++nt)
                        acc[mt][nt] = __builtin_amdgcn_mfma_f32_16x16x32_f16(af[mt], bf[nt], acc[mt][nt], 0, 0, 0);
            }
            __syncthreads();
        }
        #pragma unroll
        for (int mt = 0; mt < 2; ++mt)
            #pragma unroll
            for (int nt = 0; nt < 2; ++nt)
                #pragma unroll
                for (int r = 0; r < 4; ++r) {
                    const int m = bm * 128 + wr * 32 + mt * 16 + g * 4 + r;
                    const int n = bn * 64 + wc * 32 + nt * 16 + a;
                    __half hv = __float2half_rn(acc[mt][nt][r]);
                    qh[(size_t)m * 512 + n] = *(unsigned short*)&hv;
                }
    }

    // -------- slab sub-barrier: 16 arrivers + 16 pollers per counter --------
    __syncthreads();                  // drains every wave's q_h stores
    if (tid == 0) {
        __threadfence();              // release: cross-XCD visibility (R19-proven)
        atomicAdd(&bar[slab], 1u);
        while (__hip_atomic_load(&bar[slab], __ATOMIC_RELAXED, __HIP_MEMORY_SCOPE_AGENT) < 16u)
            __builtin_amdgcn_s_sleep(32);   // ~2k cycles between polls
    }
    __syncthreads();
    __threadfence();                  // acquire (R19-proven pattern)

    // ---------------- phase 2: flash attention (R15 body, verified) ----------------
    {
        unsigned short* KtB = (unsigned short*)LDSB;            // [2 buf][2 kv][64*72]
        unsigned short* VtB = (unsigned short*)(LDSB + 36864);  // [2 buf][2 kv][64*64]

        const int qq = wv & 3;            // q group (32 rows)
        const int kv = wv >> 2;           // key half (1024 keys)

        const unsigned short* qbh = qh + (size_t)b * SS * DD + h * HD;
        const int qrow0 = qt * 128 + qq * 32;

        frag_ab qf[2][2];
        const __half2 qsc = __float2half2_rn(0.18033688011112042f);
        #pragma unroll
        for (int nt = 0; nt < 2; ++nt)
            #pragma unroll
            for (int kh = 0; kh < 2; ++kh) {
                frag_ab t = *(const frag_ab*)(qbh + (size_t)(qrow0 + nt * 16 + a) * DD + kh * 32 + g * 8);
                __half2* phh = (__half2*)&t;
                #pragma unroll
                for (int i = 0; i < 4; ++i) phh[i] = __hmul2(phh[i], qsc);
                qf[nt][kh] = t;
            }

        frag_cd oacc[4][2] = {};          // [ft][nt] -> O^T[feature][q=a]
        float lsum[2] = {0.f, 0.f};

        const int t8 = tid & 255;
        const int f0 = (t8 & 31) * 2;
        const int u8 = t8 >> 5;
        const int r0 = u8 * 8;
        const int keybase = (tid >> 8) * 1024;
        unsigned short* KsBase = KtB + (tid >> 8) * 4608;
        unsigned short* VsBase = VtB + (tid >> 8) * 4096;
        const int vsw = (u8 ^ (t8 & 7)) << 3;

        unsigned int d[8];
        #pragma unroll
        for (int k = 0; k < 8; ++k)
            d[k] = *(const unsigned int*)(qbh + (size_t)(keybase + r0 + k) * DD + f0);

        const unsigned short* KcBase = KtB + kv * 4608;
        const unsigned short* VcBase = VtB + kv * 4096;
        const float coff = -11.541560327111707f;   // -8*log2(e)
        const int sv = (a >> 1) & 7;

        auto stage_write = [&](int buf) {
            unsigned short* Ksb = KsBase + buf * 9216;
            unsigned short* Vsb = VsBase + buf * 8192;
            #pragma unroll
            for (int k = 0; k < 8; ++k)
                *(unsigned int*)&Ksb[(r0 + k) * 72 + f0] = d[k];
            unsigned int vlo[4], vhi[4];
            #pragma unroll
            for (int j = 0; j < 4; ++j) {
                vlo[j] = (d[2 * j] & 0xFFFFu) | (d[2 * j + 1] << 16);
                vhi[j] = (d[2 * j] >> 16)     | (d[2 * j + 1] & 0xFFFF0000u);
            }
            *(uint4*)&Vsb[f0 * 64 + vsw]       = *(uint4*)vlo;
            *(uint4*)&Vsb[(f0 + 1) * 64 + vsw] = *(uint4*)vhi;
        };

        stage_write(0);
        #pragma unroll
        for (int k = 0; k < 8; ++k)
            d[k] = *(const unsigned int*)(qbh + (size_t)(keybase + 64 + r0 + k) * DD + f0);
        __syncthreads();

        for (int it = 0; it < 16; ++it) {
            const int cur = it & 1;
            if (it < 15) stage_write(cur ^ 1);
            if (it < 14) {
                const int kb = keybase + (it + 2) * 64;
                #pragma unroll
                for (int k = 0; k < 8; ++k)
                    d[k] = *(const unsigned int*)(qbh + (size_t)(kb + r0 + k) * DD + f0);
            }
            const unsigned short* Kc = KcBase + cur * 9216;
            const unsigned short* Vc = VcBase + cur * 8192;

            #pragma unroll
            for (int kt = 0; kt < 4; ++kt) {
                const frag_ab ka0 = *(const frag_ab*)&Kc[(kt * 16 + a) * 72 + g * 8];
                const frag_ab ka1 = *(const frag_ab*)&Kc[(kt * 16 + a) * 72 + 32 + g * 8];
                frag_b4 pbk[2];
                #pragma unroll
                for (int nt = 0; nt < 2; ++nt) {
                    frag_cd c = {coff, coff, coff, coff};
                    c = __builtin_amdgcn_mfma_f32_16x16x32_f16(ka0, qf[nt][0], c, 0, 0, 0);
                    c = __builtin_amdgcn_mfma_f32_16x16x32_f16(ka1, qf[nt][1], c, 0, 0, 0);
                    const float p0 = __builtin_amdgcn_exp2f(c[0]);
                    const float p1 = __builtin_amdgcn_exp2f(c[1]);
                    const float p2 = __builtin_amdgcn_exp2f(c[2]);
                    const float p3 = __builtin_amdgcn_exp2f(c[3]);
                    lsum[nt] += (p0 + p1) + (p2 + p3);
                    union { unsigned int u[2]; frag_b4 hh; } pu;
                    pu.u[0] = pack_h2(p0, p1);
                    pu.u[1] = pack_h2(p2, p3);
                    pbk[nt] = pu.hh;
                }
                const int vch = ((2 * kt + (g >> 1)) ^ sv) << 3;
                const int vof = (g & 1) << 2;
                #pragma unroll
                for (int ft = 0; ft < 4; ++ft) {
                    const frag_b4 va = *(const frag_b4*)&Vc[(ft * 16 + a) * 64 + vch + vof];
                    oacc[ft][0] = __builtin_amdgcn_mfma_f32_16x16x16f16(va, pbk[0], oacc[ft][0], 0, 0, 0);
                    oacc[ft][1] = __builtin_amdgcn_mfma_f32_16x16x16f16(va, pbk[1], oacc[ft][1], 0, 0, 0);
                }
            }
            __syncthreads();
        }

        #pragma unroll
        for (int nt = 0; nt < 2; ++nt) {
            lsum[nt] += __shfl_xor(lsum[nt], 16, 64);
            lsum[nt] += __shfl_xor(lsum[nt], 32, 64);
        }
        float* Obuf = (float*)LDSB;                   // [qq][f 64][q 32+1] = 33792 B
        float* Lbuf = (float*)(LDSB + 33792);         // [qq][q 32]
        if (kv == 1) {
            #pragma unroll
            for (int ft = 0; ft < 4; ++ft)
                #pragma unroll
                for (int nt = 0; nt < 2; ++nt)
                    #pragma unroll
                    for (int r = 0; r < 4; ++r)
                        Obuf[qq * 2112 + (ft * 16 + g * 4 + r) * 33 + nt * 16 + a] = oacc[ft][nt][r];
            if (g == 0)
                #pragma unroll
                for (int nt = 0; nt < 2; ++nt)
                    Lbuf[qq * 32 + nt * 16 + a] = lsum[nt];
        }
        __syncthreads();
        if (kv == 0) {
            #pragma unroll
            for (int nt = 0; nt < 2; ++nt) {
                const float inv = 1.f / (lsum[nt] + Lbuf[qq * 32 + nt * 16 + a]);
                float* op = out + ((size_t)b * SS + qrow0 + nt * 16 + a) * DD + h * HD;
                #pragma unroll
                for (int ft = 0; ft < 4; ++ft) {
                    const int fb = ft * 16 + g * 4;
                    float4 vv = {
                        (oacc[ft][nt][0] + Obuf[qq * 2112 + (fb + 0) * 33 + nt * 16 + a]) * inv,
                        (oacc[ft][nt][1] + Obuf[qq * 2112 + (fb + 1) * 33 + nt * 16 + a]) * inv,
                        (oacc[ft][nt][2] + Obuf[qq * 2112 + (fb + 2) * 33 + nt * 16 + a]) * inv,
                        (oacc[ft][nt][3] + Obuf[qq * 2112 + (fb + 3) * 33 + nt * 16 + a]) * inv };
                    *(float4*)(op + fb) = vv;
                }
            }
        }
    }
}

// ---------------- fallback pair (R18-exact), used only if ws_size has no slack ----------------
__global__ __launch_bounds__(512, 4) void gemm_kernel(const float* __restrict__ x,
                                                      const float* __restrict__ w,
                                                      unsigned short* __restrict__ q) {
    __shared__ __align__(16) unsigned short Ah[2][128 * 72];
    __shared__ __align__(16) unsigned short Bt[2][64 * 72];
    const int tid = threadIdx.x;
    const int lane = tid & 63, wv = tid >> 6;
    const int a = lane & 15, g = lane >> 4;
    const int bm = blockIdx.x, bn = blockIdx.y;
    const int wr = wv >> 1, wc = wv & 1;

    frag_cd acc[2][2] = {};
    const int ar = tid >> 4;
    const int ac = (tid & 15) * 4;
    const int bnw = tid & 63;
    const int bc  = tid >> 6;
    const int bp  = (bc + 2 * (bnw & 7)) & 7;

    float4 av[4];
    float  bw[8];

    auto load_tiles = [&](int k0) {
        #pragma unroll
        for (int i = 0; i < 4; ++i)
            av[i] = *(const float4*)(x + (size_t)(bm * 128 + ar + 32 * i) * 512 + k0 + ac);
        #pragma unroll
        for (int j = 0; j < 8; ++j)
            bw[j] = w[(size_t)(k0 + bc * 8 + j) * 512 + bn * 64 + bnw];
    };
    auto stage_tiles = [&](int buf) {
        #pragma unroll
        for (int i = 0; i < 4; ++i) {
            uint2 hh = { pack_h2(av[i].x, av[i].y), pack_h2(av[i].z, av[i].w) };
            *(uint2*)&Ah[buf][(ar + 32 * i) * 72 + ac] = hh;
        }
        unsigned int tb[4];
        #pragma unroll
        for (int j = 0; j < 4; ++j)
            tb[j] = pack_h2(bw[2 * j], bw[2 * j + 1]);
        *(uint4*)&Bt[buf][bnw * 72 + bp * 8] = *(uint4*)tb;
    };

    load_tiles(0);
    stage_tiles(0);
    load_tiles(64);
    __syncthreads();

    for (int it = 0; it < 8; ++it) {
        const int cur = it & 1;
        if (it < 7) stage_tiles(cur ^ 1);
        if (it < 6) load_tiles((it + 2) * 64);
        #pragma unroll
        for (int kh = 0; kh < 2; ++kh) {
            frag_ab bf[2], af[2];
            #pragma unroll
            for (int nt = 0; nt < 2; ++nt) {
                const int nr = wc * 32 + nt * 16 + a;
                const int pr = ((kh * 4 + g) + 2 * (nr & 7)) & 7;
                bf[nt] = *(const frag_ab*)&Bt[cur][nr * 72 + pr * 8];
            }
            #pragma unroll
            for (int mt = 0; mt < 2; ++mt)
                af[mt] = *(const frag_ab*)&Ah[cur][(wr * 32 + mt * 16 + a) * 72 + kh * 32 + g * 8];
            #pragma unroll
            for (int mt = 0; mt < 2; ++mt)
                #pragma unroll
                for (int nt = 0; nt < 2; ++nt)
                    acc[mt][nt] = __builtin_amdgcn_mfma_f32_16x16x32_f16(af[mt], bf[nt], acc[mt][nt], 0, 0, 0);
        }
        __syncthreads();
    }
    #pragma unroll
    for (int mt = 0; mt < 2; ++mt)
        #pragma unroll
        for (int nt = 0; nt < 2; ++nt)
            #pragma unroll
            for (int r = 0; r < 4; ++r) {
                const int m = bm * 128 + wr * 32 + mt * 16 + g * 4 + r;
                const int n = bn * 64 + wc * 32 + nt * 16 + a;
                __half hv = __float2half_rn(acc[mt][nt][r]);
                q[(size_t)m * 512 + n] = *(unsigned short*)&hv;
            }
}

__global__ __launch_bounds__(512, 4) void attn_kernel(const __half* __restrict__ qg,
                                                      float* __restrict__ out) {
    __shared__ __align__(16) unsigned char LDSB[69632];
    unsigned short* KtB = (unsigned short*)LDSB;
    unsigned short* VtB = (unsigned short*)(LDSB + 36864);

    const int tid = threadIdx.x;
    const int lane = tid & 63, wv = tid >> 6;
    const int a = lane & 15, g = lane >> 4;
    const int qq = wv & 3;
    const int kv = wv >> 2;
    const int bid = blockIdx.x;
    const int qt = bid & 15;
    const int h  = (bid >> 4) & 7;
    const int b  = bid >> 7;

    const unsigned short* qbh = (const unsigned short*)qg + (size_t)b * SS * DD + h * HD;
    const int qrow0 = qt * 128 + qq * 32;

    frag_ab qf[2][2];
    const __half2 qsc = __float2half2_rn(0.18033688011112042f);
    #pragma unroll
    for (int nt = 0; nt < 2; ++nt)
        #pragma unroll
        for (int kh = 0; kh < 2; ++kh) {
            frag_ab t = *(const frag_ab*)(qbh + (size_t)(qrow0 + nt * 16 + a) * DD + kh * 32 + g * 8);
            __half2* phh = (__half2*)&t;
            #pragma unroll
            for (int i = 0; i < 4; ++i) phh[i] = __hmul2(phh[i], qsc);
            qf[nt][kh] = t;
        }

    frag_cd oacc[4][2] = {};
    float lsum[2] = {0.f, 0.f};

    const int t8 = tid & 255;
    const int f0 = (t8 & 31) * 2;
    const int u8 = t8 >> 5;
    const int r0 = u8 * 8;
    const int keybase = (tid >> 8) * 1024;
    unsigned short* KsBase = KtB + (tid >> 8) * 4608;
    unsigned short* VsBase = VtB + (tid >> 8) * 4096;
    const int vsw = (u8 ^ (t8 & 7)) << 3;

    unsigned int d[8];
    #pragma unroll
    for (int k = 0; k < 8; ++k)
        d[k] = *(const unsigned int*)(qbh + (size_t)(keybase + r0 + k) * DD + f0);

    const unsigned short* KcBase = KtB + kv * 4608;
    const unsigned short* VcBase = VtB + kv * 4096;
    const float coff = -11.541560327111707f;
    const int sv = (a >> 1) & 7;

    auto stage_write = [&](int buf) {
        unsigned short* Ksb = KsBase + buf * 9216;
        unsigned short* Vsb = VsBase + buf * 8192;
        #pragma unroll
        for (int k = 0; k < 8; ++k)
            *(unsigned int*)&Ksb[(r0 + k) * 72 + f0] = d[k];
        unsigned int vlo[4], vhi[4];
        #pragma unroll
        for (int j = 0; j < 4; ++j) {
            vlo[j] = (d[2 * j] & 0xFFFFu) | (d[2 * j + 1] << 16);
            vhi[j] = (d[2 * j] >> 16)     | (d[2 * j + 1] & 0xFFFF0000u);
        }
        *(uint4*)&Vsb[f0 * 64 + vsw]       = *(uint4*)vlo;
        *(uint4*)&Vsb[(f0 + 1) * 64 + vsw] = *(uint4*)vhi;
    };

    stage_write(0);
    #pragma unroll
    for (int k = 0; k < 8; ++k)
        d[k] = *(const unsigned int*)(qbh + (size_t)(keybase + 64 + r0 + k) * DD + f0);
    __syncthreads();

    for (int it = 0; it < 16; ++it) {
        const int cur = it & 1;
        if (it < 15) stage_write(cur ^ 1);
        if (it < 14) {
            const int kb = keybase + (it + 2) * 64;
            #pragma unroll
            for (int k = 0; k < 8; ++k)
                d[k] = *(const unsigned int*)(qbh + (size_t)(kb + r0 + k) * DD + f0);
        }
        const unsigned short* Kc = KcBase + cur * 9216;
        const unsigned short* Vc = VcBase + cur * 8192;

        #pragma unroll
        for (int kt = 0; kt < 4; ++kt) {
            const frag_ab ka0 = *(const frag_ab*)&Kc[(kt * 16 + a) * 72 + g * 8];
            const frag_ab ka1 = *(const frag_ab*)&Kc[(kt * 16 + a) * 72 + 32 + g * 8];
            frag_b4 pbk[2];
            #pragma unroll
            for (int nt = 0; nt < 2; ++nt) {
                frag_cd c = {coff, coff, coff, coff};
                c = __builtin_amdgcn_mfma_f32_16x16x32_f16(ka0, qf[nt][0], c, 0, 0, 0);
                c = __builtin_amdgcn_mfma_f32_16x16x32_f16(ka1, qf[nt][1], c, 0, 0, 0);
                const float p0 = __builtin_amdgcn_exp2f(c[0]);
                const float p1 = __builtin_amdgcn_exp2f(c[1]);
                const float p2 = __builtin_amdgcn_exp2f(c[2]);
                const float p3 = __builtin_amdgcn_exp2f(c[3]);
                lsum[nt] += (p0 + p1) + (p2 + p3);
                union { unsigned int u[2]; frag_b4 hh; } pu;
                pu.u[0] = pack_h2(p0, p1);
                pu.u[1] = pack_h2(p2, p3);
                pbk[nt] = pu.hh;
            }
            const int vch = ((2 * kt + (g >> 1)) ^ sv) << 3;
            const int vof = (g & 1) << 2;
            #pragma unroll
            for (int ft = 0; ft < 4; ++ft) {
                const frag_b4 va = *(const frag_b4*)&Vc[(ft * 16 + a) * 64 + vch + vof];
                oacc[ft][0] = __builtin_amdgcn_mfma_f32_16x16x16f16(va, pbk[0], oacc[ft][0], 0, 0, 0);
                oacc[ft][1] = __builtin_amdgcn_mfma_f32_16x16x16f16(va, pbk[1], oacc[ft][1], 0, 0, 0);
            }
        }
        __syncthreads();
    }

    #pragma unroll
    for (int nt = 0; nt < 2; ++nt) {
        lsum[nt] += __shfl_xor(lsum[nt], 16, 64);
        lsum[nt] += __shfl_xor(lsum[nt], 32, 64);
    }
    float* Obuf = (float*)LDSB;
    float* Lbuf = (float*)(LDSB + 33792);
    if (kv == 1) {
        #pragma unroll
        for (int ft = 0; ft < 4; ++ft)
            #pragma unroll
            for (int nt = 0; nt < 2; ++nt)
                #pragma unroll
                for (int r = 0; r < 4; ++r)
                    Obuf[qq * 2112 + (ft * 16 + g * 4 + r) * 33 + nt * 16 + a] = oacc[ft][nt][r];
        if (g == 0)
            #pragma unroll
            for (int nt = 0; nt < 2; ++nt)
                Lbuf[qq * 32 + nt * 16 + a] = lsum[nt];
    }
    __syncthreads();
    if (kv == 0) {
        #pragma unroll
        for (int nt = 0; nt < 2; ++nt) {
            const float inv = 1.f / (lsum[nt] + Lbuf[qq * 32 + nt * 16 + a]);
            float* op = out + ((size_t)b * SS + qrow0 + nt * 16 + a) * DD + h * HD;
            #pragma unroll
            for (int ft = 0; ft < 4; ++ft) {
                const int fb = ft * 16 + g * 4;
                float4 vv = {
                    (oacc[ft][nt][0] + Obuf[qq * 2112 + (fb + 0) * 33 + nt * 16 + a]) * inv,
                    (oacc[ft][nt][1] + Obuf[qq * 2112 + (fb + 1) * 33 + nt * 16 + a]) * inv,
                    (oacc[ft][nt][2] + Obuf[qq * 2112 + (fb + 2) * 33 + nt * 16 + a]) * inv,
                    (oacc[ft][nt][3] + Obuf[qq * 2112 + (fb + 3) * 33 + nt * 16 + a]) * inv };
                *(float4*)(op + fb) = vv;
            }
        }
    }
}

extern "C" void kernel_launch(void* const* d_in, const int* in_sizes, int n_in,
                              void* d_out, int out_size, void* d_ws, size_t ws_size,
                              hipStream_t stream) {
    const float* x  = (const float*)d_in[0];
    const float* wq = (const float*)d_in[1];
    float* out = (float*)d_out;
    unsigned short* q_h = (unsigned short*)d_ws;            // 8 MB
    const size_t QH_BYTES = (size_t)4 * SS * DD * sizeof(unsigned short);

    if (ws_size >= QH_BYTES + 128) {
        unsigned int* bar = (unsigned int*)((char*)d_ws + QH_BYTES);
        hipMemsetAsync(bar, 0, 128, stream);
        fused_kernel<<<512, 512, 0, stream>>>(x, wq, q_h, out, bar);
    } else {
        dim3 ggrid(64, 8);
        gemm_kernel<<<ggrid, 512, 0, stream>>>(x, wq, q_h);
        attn_kernel<<<512, 512, 0, stream>>>((const __half*)q_h, out);
    }
}

// Round 11
// 120.784 us; speedup vs baseline: 2.0261x; 2.0261x over previous
//
#include <hip/hip_runtime.h>
#include <hip/hip_fp16.h>
#include <math.h>

#define SS 2048
#define DD 512
#define NH 8
#define HD 64

typedef __attribute__((ext_vector_type(8))) short frag_ab;     // 8 fp16 (x32 A/B)
typedef __attribute__((ext_vector_type(4))) float frag_cd;     // 4 fp32 (C/D)
typedef __attribute__((ext_vector_type(4))) _Float16 frag_b4;  // 4 fp16 (x16 A/B)

static __device__ inline unsigned int pack_h2(float x, float y) {
    __half2 t = __floats2half2_rn(x, y);   // x -> low half
    return *(unsigned int*)&t;
}

// ---------- GEMM v3 (R18-exact, proven): q_h = fp16(x @ Wq) ----------
// Tile 128x64, grid (64,8) = 512 blocks = 2 blocks/CU, 512 thr = 8 waves
// (4 mr x 2 nc, wave-tile 32x32).  Double-buffered LDS, one barrier/iter
// (stage it+1 || compute it, prefetch it+2).  B staged bank-clean via
// permuted-chunk swizzle p=(c+2(n&7))%8.  x-row-sharing blocks (stride-64
// ids) already land on one XCD -> x served from local L2 after first read.
__global__ __launch_bounds__(512, 4) void gemm_kernel(const float* __restrict__ x,
                                                      const float* __restrict__ w,
                                                      unsigned short* __restrict__ q) {
    __shared__ __align__(16) unsigned short Ah[2][128 * 72];
    __shared__ __align__(16) unsigned short Bt[2][64 * 72];
    const int tid = threadIdx.x;
    const int lane = tid & 63, wv = tid >> 6;
    const int a = lane & 15, g = lane >> 4;
    const int bm = blockIdx.x, bn = blockIdx.y;
    const int wr = wv >> 1, wc = wv & 1;

    frag_cd acc[2][2] = {};
    const int ar = tid >> 4;
    const int ac = (tid & 15) * 4;
    const int bnw = tid & 63;
    const int bc  = tid >> 6;
    const int bp  = (bc + 2 * (bnw & 7)) & 7;

    float4 av[4];
    float  bw[8];

    auto load_tiles = [&](int k0) {
        #pragma unroll
        for (int i = 0; i < 4; ++i)
            av[i] = *(const float4*)(x + (size_t)(bm * 128 + ar + 32 * i) * 512 + k0 + ac);
        #pragma unroll
        for (int j = 0; j < 8; ++j)
            bw[j] = w[(size_t)(k0 + bc * 8 + j) * 512 + bn * 64 + bnw];
    };
    auto stage_tiles = [&](int buf) {
        #pragma unroll
        for (int i = 0; i < 4; ++i) {
            uint2 hh = { pack_h2(av[i].x, av[i].y), pack_h2(av[i].z, av[i].w) };
            *(uint2*)&Ah[buf][(ar + 32 * i) * 72 + ac] = hh;
        }
        unsigned int tb[4];
        #pragma unroll
        for (int j = 0; j < 4; ++j)
            tb[j] = pack_h2(bw[2 * j], bw[2 * j + 1]);
        *(uint4*)&Bt[buf][bnw * 72 + bp * 8] = *(uint4*)tb;
    };

    load_tiles(0);
    stage_tiles(0);
    load_tiles(64);
    __syncthreads();

    for (int it = 0; it < 8; ++it) {
        const int cur = it & 1;
        if (it < 7) stage_tiles(cur ^ 1);
        if (it < 6) load_tiles((it + 2) * 64);
        #pragma unroll
        for (int kh = 0; kh < 2; ++kh) {
            frag_ab bf[2], af[2];
            #pragma unroll
            for (int nt = 0; nt < 2; ++nt) {
                const int nr = wc * 32 + nt * 16 + a;
                const int pr = ((kh * 4 + g) + 2 * (nr & 7)) & 7;
                bf[nt] = *(const frag_ab*)&Bt[cur][nr * 72 + pr * 8];
            }
            #pragma unroll
            for (int mt = 0; mt < 2; ++mt)
                af[mt] = *(const frag_ab*)&Ah[cur][(wr * 32 + mt * 16 + a) * 72 + kh * 32 + g * 8];
            #pragma unroll
            for (int mt = 0; mt < 2; ++mt)
                #pragma unroll
                for (int nt = 0; nt < 2; ++nt)
                    acc[mt][nt] = __builtin_amdgcn_mfma_f32_16x16x32_f16(af[mt], bf[nt], acc[mt][nt], 0, 0, 0);
        }
        __syncthreads();
    }
    #pragma unroll
    for (int mt = 0; mt < 2; ++mt)
        #pragma unroll
        for (int nt = 0; nt < 2; ++nt)
            #pragma unroll
            for (int r = 0; r < 4; ++r) {
                const int m = bm * 128 + wr * 32 + mt * 16 + g * 4 + r;
                const int n = bn * 64 + wc * 32 + nt * 16 + a;
                __half hv = __float2half_rn(acc[mt][nt][r]);
                q[(size_t)m * 512 + n] = *(unsigned short*)&hv;
            }
}

// ---------- Flash attention, R21 = R18 body + slab-XCD block remap ----------
// R18 measured: FETCH 35 MB vs 8 MB unique q_h => ~4x HBM over-fetch.  The
// 16 blocks of slab (b,h) all stage the SAME 256 KB q_h column-slab; with
// R18's bid = qt + 16h + 128b (qt fastest) they round-robin across XCDs, so
// the slab is fetched into up to 8 different L2s.  R21 remap: bid = slab +
// 32*qt -> slab-mates share id residue mod 8 -> one XCD -> slab L2-resident
// after first read.  Pure bijective index change; body byte-identical R18.
__global__ __launch_bounds__(512, 4) void attn_kernel(const __half* __restrict__ qg,
                                                      float* __restrict__ out) {
    __shared__ __align__(16) unsigned char LDSB[69632];
    unsigned short* KtB = (unsigned short*)LDSB;            // [2 buf][2 kv][64*72]
    unsigned short* VtB = (unsigned short*)(LDSB + 36864);  // [2 buf][2 kv][64*64]

    const int tid = threadIdx.x;
    const int lane = tid & 63, wv = tid >> 6;
    const int a = lane & 15, g = lane >> 4;
    const int qq = wv & 3;            // q group (32 rows)
    const int kv = wv >> 2;           // key half (1024 keys)
    const int bid = blockIdx.x;       // 512 = 32(slab = h + 8b) x 16(qt)
    const int slab = bid & 31;        // slab-mates: stride-32 ids == same XCD
    const int qt = bid >> 5;
    const int h  = slab & 7;
    const int b  = slab >> 3;

    const unsigned short* qbh = (const unsigned short*)qg + (size_t)b * SS * DD + h * HD;
    const int qrow0 = qt * 128 + qq * 32;

    // Q B-fragments, pre-scaled by 0.125*log2(e)
    frag_ab qf[2][2];
    const __half2 qsc = __float2half2_rn(0.18033688011112042f);
    #pragma unroll
    for (int nt = 0; nt < 2; ++nt)
        #pragma unroll
        for (int kh = 0; kh < 2; ++kh) {
            frag_ab t = *(const frag_ab*)(qbh + (size_t)(qrow0 + nt * 16 + a) * DD + kh * 32 + g * 8);
            __half2* phh = (__half2*)&t;
            #pragma unroll
            for (int i = 0; i < 4; ++i) phh[i] = __hmul2(phh[i], qsc);
            qf[nt][kh] = t;
        }

    frag_cd oacc[4][2] = {};          // [ft][nt] -> O^T[feature][q=a]
    float lsum[2] = {0.f, 0.f};

    // staging: threads 0-255 stage key-half 0, 256-511 half 1 (== own wave's kv)
    const int t8 = tid & 255;
    const int f0 = (t8 & 31) * 2;     // feature column (even)
    const int u8 = t8 >> 5;           // key chunk 0..7
    const int r0 = u8 * 8;
    const int keybase = (tid >> 8) * 1024;
    unsigned short* KsBase = KtB + (tid >> 8) * 4608;
    unsigned short* VsBase = VtB + (tid >> 8) * 4096;
    const int vsw = (u8 ^ (t8 & 7)) << 3;   // s(f) = (f>>1)&7

    unsigned int d[8];
    #pragma unroll
    for (int k = 0; k < 8; ++k)
        d[k] = *(const unsigned int*)(qbh + (size_t)(keybase + r0 + k) * DD + f0);

    const unsigned short* KcBase = KtB + kv * 4608;
    const unsigned short* VcBase = VtB + kv * 4096;
    const float coff = -11.541560327111707f;   // -8*log2(e): p = 2^(s' + coff) = e^(s-8)
    const int sv = (a >> 1) & 7;               // V read swizzle

    auto stage_write = [&](int buf) {
        unsigned short* Ksb = KsBase + buf * 9216;
        unsigned short* Vsb = VsBase + buf * 8192;
        #pragma unroll
        for (int k = 0; k < 8; ++k)   // K key-major, stride 72 (floor-rate)
            *(unsigned int*)&Ksb[(r0 + k) * 72 + f0] = d[k];
        unsigned int vlo[4], vhi[4];
        #pragma unroll
        for (int j = 0; j < 4; ++j) {
            vlo[j] = (d[2 * j] & 0xFFFFu) | (d[2 * j + 1] << 16);
            vhi[j] = (d[2 * j] >> 16)     | (d[2 * j + 1] & 0xFFFF0000u);
        }
        *(uint4*)&Vsb[f0 * 64 + vsw]       = *(uint4*)vlo;
        *(uint4*)&Vsb[(f0 + 1) * 64 + vsw] = *(uint4*)vhi;
    };

    stage_write(0);                   // tile 0 -> buf 0
    #pragma unroll
    for (int k = 0; k < 8; ++k)       // tile 1 -> regs
        d[k] = *(const unsigned int*)(qbh + (size_t)(keybase + 64 + r0 + k) * DD + f0);
    __syncthreads();

    for (int it = 0; it < 16; ++it) {
        const int cur = it & 1;
        if (it < 15) stage_write(cur ^ 1);     // tile it+1 -> other buf
        if (it < 14) {                          // tile it+2 -> regs
            const int kb = keybase + (it + 2) * 64;
            #pragma unroll
            for (int k = 0; k < 8; ++k)
                d[k] = *(const unsigned int*)(qbh + (size_t)(kb + r0 + k) * DD + f0);
        }
        const unsigned short* Kc = KcBase + cur * 9216;
        const unsigned short* Vc = VcBase + cur * 8192;

        // ---- per 16-key slice: S^T = K.Q^T -> exp2 -> pack == PV B-frag -> PV ----
        #pragma unroll
        for (int kt = 0; kt < 4; ++kt) {
            const frag_ab ka0 = *(const frag_ab*)&Kc[(kt * 16 + a) * 72 + g * 8];
            const frag_ab ka1 = *(const frag_ab*)&Kc[(kt * 16 + a) * 72 + 32 + g * 8];
            frag_b4 pbk[2];
            #pragma unroll
            for (int nt = 0; nt < 2; ++nt) {
                frag_cd c = {coff, coff, coff, coff};
                c = __builtin_amdgcn_mfma_f32_16x16x32_f16(ka0, qf[nt][0], c, 0, 0, 0);
                c = __builtin_amdgcn_mfma_f32_16x16x32_f16(ka1, qf[nt][1], c, 0, 0, 0);
                const float p0 = __builtin_amdgcn_exp2f(c[0]);
                const float p1 = __builtin_amdgcn_exp2f(c[1]);
                const float p2 = __builtin_amdgcn_exp2f(c[2]);
                const float p3 = __builtin_amdgcn_exp2f(c[3]);
                lsum[nt] += (p0 + p1) + (p2 + p3);
                union { unsigned int u[2]; frag_b4 hh; } pu;
                pu.u[0] = pack_h2(p0, p1);   // keys 16kt+4g+0,1  (B-frag k=4g+0,1)
                pu.u[1] = pack_h2(p2, p3);   // keys 16kt+4g+2,3  (B-frag k=4g+2,3)
                pbk[nt] = pu.hh;
            }
            const int vch = ((2 * kt + (g >> 1)) ^ sv) << 3;   // swizzled 8-key chunk
            const int vof = (g & 1) << 2;                      // 4-key offset in chunk
            #pragma unroll
            for (int ft = 0; ft < 4; ++ft) {
                const frag_b4 va = *(const frag_b4*)&Vc[(ft * 16 + a) * 64 + vch + vof];
                oacc[ft][0] = __builtin_amdgcn_mfma_f32_16x16x16f16(va, pbk[0], oacc[ft][0], 0, 0, 0);
                oacc[ft][1] = __builtin_amdgcn_mfma_f32_16x16x16f16(va, pbk[1], oacc[ft][1], 0, 0, 0);
            }
        }
        __syncthreads();              // separates iterations (buffers alternate)
    }

    // ---- in-block combine: kv=1 -> LDS; kv=0 adds, normalizes, writes ----
    #pragma unroll
    for (int nt = 0; nt < 2; ++nt) {
        lsum[nt] += __shfl_xor(lsum[nt], 16, 64);
        lsum[nt] += __shfl_xor(lsum[nt], 32, 64);
    }
    float* Obuf = (float*)LDSB;                   // [qq][f 64][q 32+1 pad] = 33792 B
    float* Lbuf = (float*)(LDSB + 33792);         // [qq][q 32] = 512 B
    if (kv == 1) {
        #pragma unroll
        for (int ft = 0; ft < 4; ++ft)
            #pragma unroll
            for (int nt = 0; nt < 2; ++nt)
                #pragma unroll
                for (int r = 0; r < 4; ++r)
                    Obuf[qq * 2112 + (ft * 16 + g * 4 + r) * 33 + nt * 16 + a] = oacc[ft][nt][r];
        if (g == 0)
            #pragma unroll
            for (int nt = 0; nt < 2; ++nt)
                Lbuf[qq * 32 + nt * 16 + a] = lsum[nt];
    }
    __syncthreads();
    if (kv == 0) {
        #pragma unroll
        for (int nt = 0; nt < 2; ++nt) {
            const float inv = 1.f / (lsum[nt] + Lbuf[qq * 32 + nt * 16 + a]);
            float* op = out + ((size_t)b * SS + qrow0 + nt * 16 + a) * DD + h * HD;
            #pragma unroll
            for (int ft = 0; ft < 4; ++ft) {
                const int fb = ft * 16 + g * 4;
                float4 vv = {
                    (oacc[ft][nt][0] + Obuf[qq * 2112 + (fb + 0) * 33 + nt * 16 + a]) * inv,
                    (oacc[ft][nt][1] + Obuf[qq * 2112 + (fb + 1) * 33 + nt * 16 + a]) * inv,
                    (oacc[ft][nt][2] + Obuf[qq * 2112 + (fb + 2) * 33 + nt * 16 + a]) * inv,
                    (oacc[ft][nt][3] + Obuf[qq * 2112 + (fb + 3) * 33 + nt * 16 + a]) * inv };
                *(float4*)(op + fb) = vv;
            }
        }
    }
}

extern "C" void kernel_launch(void* const* d_in, const int* in_sizes, int n_in,
                              void* d_out, int out_size, void* d_ws, size_t ws_size,
                              hipStream_t stream) {
    const float* x  = (const float*)d_in[0];
    const float* wq = (const float*)d_in[1];
    float* out = (float*)d_out;
    unsigned short* q_h = (unsigned short*)d_ws;   // 8 MB

    dim3 ggrid(64, 8);
    gemm_kernel<<<ggrid, 512, 0, stream>>>(x, wq, q_h);
    attn_kernel<<<512, 512, 0, stream>>>((const __half*)q_h, out);
}